// Round 2
// baseline (10631.608 us; speedup 1.0000x reference)
//
#include <hip/hip_runtime.h>
#include <hip/hip_bf16.h>
#include <math.h>

#define LAG   8192
#define NROW  32768        // LAG * 4 tweets
#define DIMD  1024

// ============================================================================
// fp32 tiled GEMM: C[M,1024] = act(A @ B + bias), M set by gridDim.y*128.
// block tile 128x128, BK=16, 256 threads, 8x8 microtile.
// FUSE_ADD: A := A + A2 elementwise (fuses x = text + pos_embed).
// TRANS_B:  C = A @ B^T (B row-major [1024,1024], read as B[col,k]).
// ============================================================================
template<bool FUSE_ADD, bool BIAS, bool RELU, bool TRANS_B>
__global__ __launch_bounds__(256) void gemm_kernel(
    const float* __restrict__ A, const float* __restrict__ A2,
    const float* __restrict__ B, const float* __restrict__ bias,
    float* __restrict__ C)
{
    __shared__ float As[16][132];   // k-major (transposed on store), +4 pad
    __shared__ float Bs[16][132];
    const int tid  = threadIdx.x;
    const int tx   = tid & 15;      // column group
    const int ty   = tid >> 4;      // row group
    const int row0 = blockIdx.y * 128;
    const int col0 = blockIdx.x * 128;

    float acc[8][8];
    #pragma unroll
    for (int i = 0; i < 8; ++i)
        #pragma unroll
        for (int j = 0; j < 8; ++j) acc[i][j] = 0.f;

    for (int k0 = 0; k0 < DIMD; k0 += 16) {
        #pragma unroll
        for (int t = 0; t < 2; ++t) {
            int i  = tid + t * 256;
            int ar = i >> 2, ak = (i & 3) << 2;
            float4 av = *(const float4*)(A + (size_t)(row0 + ar) * DIMD + k0 + ak);
            if (FUSE_ADD) {
                float4 pv = *(const float4*)(A2 + (size_t)(row0 + ar) * DIMD + k0 + ak);
                av.x += pv.x; av.y += pv.y; av.z += pv.z; av.w += pv.w;
            }
            As[ak + 0][ar] = av.x;
            As[ak + 1][ar] = av.y;
            As[ak + 2][ar] = av.z;
            As[ak + 3][ar] = av.w;
            if constexpr (TRANS_B) {
                // B[col, k] layout: stage like A (transpose into k-major LDS)
                float4 bv4 = *(const float4*)(B + (size_t)(col0 + ar) * DIMD + k0 + ak);
                Bs[ak + 0][ar] = bv4.x;
                Bs[ak + 1][ar] = bv4.y;
                Bs[ak + 2][ar] = bv4.z;
                Bs[ak + 3][ar] = bv4.w;
            } else {
                int br = i >> 5, bc = (i & 31) << 2;
                *(float4*)&Bs[br][bc] =
                    *(const float4*)(B + (size_t)(k0 + br) * DIMD + col0 + bc);
            }
        }
        __syncthreads();
        #pragma unroll
        for (int kk = 0; kk < 16; ++kk) {
            float a[8], b[8];
            *(float4*)&a[0] = *(const float4*)&As[kk][ty * 8];
            *(float4*)&a[4] = *(const float4*)&As[kk][ty * 8 + 4];
            *(float4*)&b[0] = *(const float4*)&Bs[kk][tx * 4];
            *(float4*)&b[4] = *(const float4*)&Bs[kk][64 + tx * 4];
            #pragma unroll
            for (int i = 0; i < 8; ++i)
                #pragma unroll
                for (int j = 0; j < 8; ++j)
                    acc[i][j] = fmaf(a[i], b[j], acc[i][j]);
        }
        __syncthreads();
    }

    float bv[8];
    if constexpr (BIAS) {
        #pragma unroll
        for (int j = 0; j < 4; ++j) bv[j]     = bias[col0 + tx * 4 + j];
        #pragma unroll
        for (int j = 0; j < 4; ++j) bv[4 + j] = bias[col0 + 64 + tx * 4 + j];
    }
    #pragma unroll
    for (int i = 0; i < 8; ++i) {
        size_t r = (size_t)(row0 + ty * 8 + i) * DIMD;
        float4 o0, o1;
        float* p0 = (float*)&o0; float* p1 = (float*)&o1;
        #pragma unroll
        for (int j = 0; j < 4; ++j) {
            float v0 = acc[i][j];
            float v1 = acc[i][4 + j];
            if constexpr (BIAS) { v0 += bv[j]; v1 += bv[4 + j]; }
            if constexpr (RELU) { v0 = fmaxf(v0, 0.f); v1 = fmaxf(v1, 0.f); }
            p0[j] = v0; p1[j] = v1;
        }
        *(float4*)(C + r + col0 + tx * 4)      = o0;
        *(float4*)(C + r + col0 + 64 + tx * 4) = o1;
    }
}

// ============================================================================
// Multi-head (16) self-attention over k=4, IN-PLACE: o written over q.
// Safe: wave qi reads only q[qi, head slice] before writing o[qi, head slice];
// k/v rows are never written. One block per lag, wave = query row.
// ============================================================================
__global__ __launch_bounds__(256) void attn1_kernel(
    float* q, const float* __restrict__ k, const float* __restrict__ v)
{
    const int l    = blockIdx.x;
    const int qi   = threadIdx.x >> 6;
    const int lane = threadIdx.x & 63;
    const size_t base = (size_t)l * 4 * DIMD;
    const float scale = 0.125f;     // 1/sqrt(64)

    #pragma unroll 1
    for (int h = 0; h < 16; ++h) {
        int off = h * 64 + lane;
        float qv = q[base + qi * DIMD + off];
        float s0 = qv * k[base + 0 * DIMD + off];
        float s1 = qv * k[base + 1 * DIMD + off];
        float s2 = qv * k[base + 2 * DIMD + off];
        float s3 = qv * k[base + 3 * DIMD + off];
        #pragma unroll
        for (int d = 1; d < 64; d <<= 1) {
            s0 += __shfl_xor(s0, d);
            s1 += __shfl_xor(s1, d);
            s2 += __shfl_xor(s2, d);
            s3 += __shfl_xor(s3, d);
        }
        s0 *= scale; s1 *= scale; s2 *= scale; s3 *= scale;
        float mx = fmaxf(fmaxf(s0, s1), fmaxf(s2, s3));
        float e0 = expf(s0 - mx), e1 = expf(s1 - mx);
        float e2 = expf(s2 - mx), e3 = expf(s3 - mx);
        float inv = 1.f / (e0 + e1 + e2 + e3);
        e0 *= inv; e1 *= inv; e2 *= inv; e3 *= inv;
        float r = e0 * v[base + 0 * DIMD + off] + e1 * v[base + 1 * DIMD + off]
                + e2 * v[base + 2 * DIMD + off] + e3 * v[base + 3 * DIMD + off];
        q[base + qi * DIMD + off] = r;      // all q reads for head h done above
    }
}

// ============================================================================
// Single-head attention, algebraically fused:
//   scores s[qi,kk] = t[qi]·x[kk] / 32   with t = x @ (Wq2 Wk2^T)
//   m[qi]          = sum_kk softmax(s)[qi,kk] * vo[kk]  with vo = x @ (Wv2 Wo2)
// Writes m IN-PLACE over t (wave qi touches only t row qi, reads-then-writes).
// ============================================================================
__global__ __launch_bounds__(256) void attn2_kernel(
    const float* __restrict__ x, const float* __restrict__ vo, float* t)
{
    const int l    = blockIdx.x;
    const int qi   = threadIdx.x >> 6;
    const int lane = threadIdx.x & 63;
    const size_t base = (size_t)l * 4 * DIMD;

    float s0 = 0.f, s1 = 0.f, s2 = 0.f, s3 = 0.f;
    #pragma unroll
    for (int c = 0; c < 16; ++c) {
        int off = c * 64 + lane;
        float tv = t[base + qi * DIMD + off];
        s0 = fmaf(tv, x[base + 0 * DIMD + off], s0);
        s1 = fmaf(tv, x[base + 1 * DIMD + off], s1);
        s2 = fmaf(tv, x[base + 2 * DIMD + off], s2);
        s3 = fmaf(tv, x[base + 3 * DIMD + off], s3);
    }
    #pragma unroll
    for (int d = 1; d < 64; d <<= 1) {
        s0 += __shfl_xor(s0, d);
        s1 += __shfl_xor(s1, d);
        s2 += __shfl_xor(s2, d);
        s3 += __shfl_xor(s3, d);
    }
    const float scale = 0.03125f;   // 1/sqrt(1024)
    s0 *= scale; s1 *= scale; s2 *= scale; s3 *= scale;
    float mx = fmaxf(fmaxf(s0, s1), fmaxf(s2, s3));
    float e0 = expf(s0 - mx), e1 = expf(s1 - mx);
    float e2 = expf(s2 - mx), e3 = expf(s3 - mx);
    float inv = 1.f / (e0 + e1 + e2 + e3);
    e0 *= inv; e1 *= inv; e2 *= inv; e3 *= inv;
    #pragma unroll
    for (int c = 0; c < 16; ++c) {
        int off = c * 64 + lane;
        float r = e0 * vo[base + 0 * DIMD + off] + e1 * vo[base + 1 * DIMD + off]
                + e2 * vo[base + 2 * DIMD + off] + e3 * vo[base + 3 * DIMD + off];
        t[base + qi * DIMD + off] = r;
    }
}

// ============================================================================
// y = LayerNorm(inter + text + pos) * g + b     (one wave per row)
// ============================================================================
__global__ __launch_bounds__(256) void ln_kernel(
    const float* __restrict__ inter, const float* __restrict__ text,
    const float* __restrict__ pos, const float* __restrict__ g,
    const float* __restrict__ b, float* __restrict__ y)
{
    const int row  = blockIdx.x * 4 + (threadIdx.x >> 6);
    const int lane = threadIdx.x & 63;
    const size_t base = (size_t)row * DIMD;
    float v[16];
    float s = 0.f;
    #pragma unroll
    for (int c = 0; c < 16; ++c) {
        int off = c * 64 + lane;
        v[c] = inter[base + off] + text[base + off] + pos[base + off];
        s += v[c];
    }
    #pragma unroll
    for (int d = 1; d < 64; d <<= 1) s += __shfl_xor(s, d);
    float mu = s * (1.f / 1024.f);
    float vs = 0.f;
    #pragma unroll
    for (int c = 0; c < 16; ++c) { float t = v[c] - mu; vs += t * t; }
    #pragma unroll
    for (int d = 1; d < 64; d <<= 1) vs += __shfl_xor(vs, d);
    float rs = rsqrtf(vs * (1.f / 1024.f) + 1e-5f);
    #pragma unroll
    for (int c = 0; c < 16; ++c) {
        int off = c * 64 + lane;
        y[base + off] = (v[c] - mu) * rs * g[off] + b[off];
    }
}

// ============================================================================
// att = softmax(w_u^T @ tanh(w_m)) -- one block, 1024 threads, no atomics.
// ============================================================================
__global__ __launch_bounds__(1024) void att_kernel(
    const float* __restrict__ w_u, const float* __restrict__ w_m,
    float* __restrict__ att)
{
    __shared__ float tj[1024];
    __shared__ float red[16];
    const int tid = threadIdx.x;
    tj[tid] = tanhf(w_m[tid]);
    __syncthreads();
    float a = 0.f;
    #pragma unroll 8
    for (int j = 0; j < 1024; ++j)
        a = fmaf(w_u[(size_t)j * 1024 + tid], tj[j], a);
    // block max
    float m = a;
    #pragma unroll
    for (int d = 1; d < 64; d <<= 1) m = fmaxf(m, __shfl_xor(m, d));
    if ((tid & 63) == 0) red[tid >> 6] = m;
    __syncthreads();
    if (tid < 16) {
        float x = red[tid];
        #pragma unroll
        for (int d = 1; d < 16; d <<= 1) x = fmaxf(x, __shfl_xor(x, d));
        red[tid] = x;
    }
    __syncthreads();
    float mx = red[0];
    float e = expf(a - mx);
    float s = e;
    #pragma unroll
    for (int d = 1; d < 64; d <<= 1) s += __shfl_xor(s, d);
    __syncthreads();                 // all reads of red[0] done before reuse
    if ((tid & 63) == 0) red[tid >> 6] = s;
    __syncthreads();
    if (tid < 16) {
        float x = red[tid];
        #pragma unroll
        for (int d = 1; d < 16; d <<= 1) x += __shfl_xor(x, d);
        red[tid] = x;
    }
    __syncthreads();
    att[tid] = e / red[0];
}

// ============================================================================
// out_k[l,k] = m[l,k,:]·att ; lstm_in[l] = [out_k, prices] ;
// pre[l][unit*4 + {i,f,g,o}] = lstm_in @ Wih^T + bih + bhh  (grouped for LSTM)
// ============================================================================
__global__ __launch_bounds__(256) void outk_kernel(
    const float* __restrict__ m, const float* __restrict__ prices,
    const float* __restrict__ att, const float* __restrict__ Wih,
    const float* __restrict__ bih, const float* __restrict__ bhh,
    float* __restrict__ lstm_in, float* __restrict__ pre)
{
    const int l    = blockIdx.x;
    const int w    = threadIdx.x >> 6;
    const int lane = threadIdx.x & 63;
    __shared__ float li[9];
    float acc = 0.f;
    const size_t base = ((size_t)l * 4 + w) * DIMD;
    #pragma unroll
    for (int c = 0; c < 16; ++c) {
        int off = c * 64 + lane;
        acc = fmaf(m[base + off], att[off], acc);
    }
    #pragma unroll
    for (int d = 1; d < 64; d <<= 1) acc += __shfl_xor(acc, d);
    if (lane == 0) li[w] = acc;
    if (threadIdx.x >= 64 && threadIdx.x < 69)
        li[4 + threadIdx.x - 64] = prices[(size_t)l * 5 + threadIdx.x - 64];
    __syncthreads();
    if (threadIdx.x < 9) lstm_in[(size_t)l * 9 + threadIdx.x] = li[threadIdx.x];
    if (threadIdx.x < 20) {
        int g = threadIdx.x;
        float p = bih[g] + bhh[g];
        #pragma unroll
        for (int j = 0; j < 9; ++j) p = fmaf(li[j], Wih[g * 9 + j], p);
        pre[(size_t)l * 20 + (g % 5) * 4 + (g / 5)] = p;
    }
}

// ============================================================================
// Sequential LSTM: single wave; lanes 0..4 own one hidden unit each (all 4
// gates), h broadcast via readlane, 8-deep register prefetch on pre[].
// ============================================================================
__device__ __forceinline__ float bcast(float x, int srclane) {
    return __uint_as_float(__builtin_amdgcn_readlane(__float_as_uint(x), srclane));
}

__global__ __launch_bounds__(64) void lstm_kernel(
    const float* __restrict__ pre, const float* __restrict__ Whh,
    float* __restrict__ hs)
{
    const int lane = threadIdx.x;
    const int m    = (lane < 5) ? lane : 0;
    float wi[5], wf[5], wg[5], wo[5];
    #pragma unroll
    for (int j = 0; j < 5; ++j) {
        wi[j] = Whh[( 0 + m) * 5 + j];
        wf[j] = Whh[( 5 + m) * 5 + j];
        wg[j] = Whh[(10 + m) * 5 + j];
        wo[j] = Whh[(15 + m) * 5 + j];
    }
    float cm = 0.f, hm = 0.f;
    float sh0 = 0.f, sh1 = 0.f, sh2 = 0.f, sh3 = 0.f, sh4 = 0.f;

    float4 buf[8];
    #pragma unroll
    for (int j = 0; j < 8; ++j)
        buf[j] = *(const float4*)(pre + (size_t)j * 20 + m * 4);

    for (int l0 = 0; l0 < LAG; l0 += 8) {
        #pragma unroll
        for (int j = 0; j < 8; ++j) {
            float4 p = buf[j];
            // prefetch 8 steps ahead (pre[] is padded past LAG)
            buf[j] = *(const float4*)(pre + (size_t)(l0 + 8 + j) * 20 + m * 4);
            float gi = p.x, gf = p.y, gg = p.z, go = p.w;
            gi = fmaf(sh0, wi[0], gi); gf = fmaf(sh0, wf[0], gf);
            gg = fmaf(sh0, wg[0], gg); go = fmaf(sh0, wo[0], go);
            gi = fmaf(sh1, wi[1], gi); gf = fmaf(sh1, wf[1], gf);
            gg = fmaf(sh1, wg[1], gg); go = fmaf(sh1, wo[1], go);
            gi = fmaf(sh2, wi[2], gi); gf = fmaf(sh2, wf[2], gf);
            gg = fmaf(sh2, wg[2], gg); go = fmaf(sh2, wo[2], go);
            gi = fmaf(sh3, wi[3], gi); gf = fmaf(sh3, wf[3], gf);
            gg = fmaf(sh3, wg[3], gg); go = fmaf(sh3, wo[3], go);
            gi = fmaf(sh4, wi[4], gi); gf = fmaf(sh4, wf[4], gf);
            gg = fmaf(sh4, wg[4], gg); go = fmaf(sh4, wo[4], go);
            float si = 1.f / (1.f + expf(-gi));
            float sf = 1.f / (1.f + expf(-gf));
            float tg = tanhf(gg);
            float so = 1.f / (1.f + expf(-go));
            cm = fmaf(sf, cm, si * tg);
            hm = so * tanhf(cm);
            if (lane < 5) hs[(size_t)(l0 + j) * 5 + m] = hm;
            sh0 = bcast(hm, 0); sh1 = bcast(hm, 1); sh2 = bcast(hm, 2);
            sh3 = bcast(hm, 3); sh4 = bcast(hm, 4);
        }
    }
}

// ============================================================================
// final / auxiliary heads: feat=[lstm_in(9), hs(5)] @ Wt/Wa + bias
// ============================================================================
__global__ __launch_bounds__(256) void final_kernel(
    const float* __restrict__ lstm_in, const float* __restrict__ hs,
    const float* __restrict__ Wt, const float* __restrict__ bt,
    const float* __restrict__ Wa, const float* __restrict__ ba,
    float* __restrict__ out)
{
    const int l = blockIdx.x * 256 + threadIdx.x;   // 0..8191
    float f[14];
    #pragma unroll
    for (int j = 0; j < 9; ++j) f[j] = lstm_in[(size_t)l * 9 + j];
    #pragma unroll
    for (int j = 0; j < 5; ++j) f[9 + j] = hs[(size_t)l * 5 + j];
    #pragma unroll
    for (int c = 0; c < 2; ++c) {
        float a = bt[c], b = ba[c];
        #pragma unroll
        for (int j = 0; j < 14; ++j) {
            a = fmaf(f[j], Wt[j * 2 + c], a);
            b = fmaf(f[j], Wa[j * 2 + c], b);
        }
        out[(size_t)l * 2 + c]         = a;
        out[16384 + (size_t)l * 2 + c] = b;
    }
}

// ============================================================================
extern "C" void kernel_launch(void* const* d_in, const int* in_sizes, int n_in,
                              void* d_out, int out_size, void* d_ws, size_t ws_size,
                              hipStream_t stream)
{
    const float* text   = (const float*)d_in[0];
    const float* prices = (const float*)d_in[1];
    const float* pos    = (const float*)d_in[2];
    const float* Wq1    = (const float*)d_in[3];
    const float* Wk1    = (const float*)d_in[4];
    const float* Wv1    = (const float*)d_in[5];
    const float* Wo1    = (const float*)d_in[6];
    const float* ln_g   = (const float*)d_in[7];
    const float* ln_b   = (const float*)d_in[8];
    const float* W1     = (const float*)d_in[9];
    const float* b1     = (const float*)d_in[10];
    const float* W2     = (const float*)d_in[11];
    const float* b2     = (const float*)d_in[12];
    const float* Wq2    = (const float*)d_in[13];
    const float* Wk2    = (const float*)d_in[14];
    const float* Wv2    = (const float*)d_in[15];
    const float* Wo2    = (const float*)d_in[16];
    const float* w_u    = (const float*)d_in[17];
    const float* w_m    = (const float*)d_in[18];
    const float* Wih    = (const float*)d_in[19];
    const float* Whh    = (const float*)d_in[20];
    const float* bih    = (const float*)d_in[21];
    const float* bhh    = (const float*)d_in[22];
    const float* Wt     = (const float*)d_in[23];
    const float* bt     = (const float*)d_in[24];
    const float* Wa     = (const float*)d_in[25];
    const float* ba     = (const float*)d_in[26];

    float* ws = (float*)d_ws;
    const size_t BUF = (size_t)NROW * DIMD;      // 33,554,432 floats
    float* A = ws;
    float* Bb = ws + BUF;
    float* Cc = ws + 2 * BUF;
    float* Wqk     = ws + 3 * BUF;               // [1024,1024]
    float* Wvo     = Wqk + (size_t)DIMD * DIMD;  // [1024,1024]
    float* att     = Wvo + (size_t)DIMD * DIMD;  // [1024]
    float* lstm_in = att + 1024;                 // [LAG,9]
    float* pre     = lstm_in + (size_t)LAG * 9;  // [LAG,20] + 320 pad
    float* hs      = pre + ((size_t)LAG * 20 + 320);
    float* out     = (float*)d_out;
    // total ws use: 3*BUF + ~2.38M floats = ~412.2 MB

    dim3 ggrid(8, 256), gblk(256);               // M=32768 GEMMs
    dim3 sgrid(8, 8);                            // M=1024 GEMMs

    // small precomputes (independent of the big pipeline)
    att_kernel<<<1, 1024, 0, stream>>>(w_u, w_m, att);
    gemm_kernel<false, false, false, true ><<<sgrid, gblk, 0, stream>>>(Wq2, nullptr, Wk2, nullptr, Wqk);  // Wq2 @ Wk2^T
    gemm_kernel<false, false, false, false><<<sgrid, gblk, 0, stream>>>(Wv2, nullptr, Wo2, nullptr, Wvo);  // Wv2 @ Wo2

    // transformer encoder
    gemm_kernel<true , false, false, false><<<ggrid, gblk, 0, stream>>>(text, pos, Wq1, nullptr, A);
    gemm_kernel<true , false, false, false><<<ggrid, gblk, 0, stream>>>(text, pos, Wk1, nullptr, Bb);
    gemm_kernel<true , false, false, false><<<ggrid, gblk, 0, stream>>>(text, pos, Wv1, nullptr, Cc);
    attn1_kernel<<<LAG, 256, 0, stream>>>(A, Bb, Cc);                     // o -> A
    gemm_kernel<false, false, false, false><<<ggrid, gblk, 0, stream>>>(A, nullptr, Wo1, nullptr, Bb);   // inter
    ln_kernel  <<<LAG, 256, 0, stream>>>(Bb, text, pos, ln_g, ln_b, Cc);  // y
    gemm_kernel<false, true , true , false><<<ggrid, gblk, 0, stream>>>(Cc, nullptr, W1, b1, A);         // relu(y@W1+b1)
    gemm_kernel<false, true , false, false><<<ggrid, gblk, 0, stream>>>(A, nullptr, W2, b2, Bb);         // ffn
    gemm_kernel<false, false, false, false><<<ggrid, gblk, 0, stream>>>(Bb, nullptr, Wqk, nullptr, A);   // t = ffn@Wqk
    gemm_kernel<false, false, false, false><<<ggrid, gblk, 0, stream>>>(Bb, nullptr, Wvo, nullptr, Cc);  // vo = ffn@Wvo
    attn2_kernel<<<LAG, 256, 0, stream>>>(Bb, Cc, A);                     // m -> A

    // temporal head
    outk_kernel <<<LAG, 256, 0, stream>>>(A, prices, att, Wih, bih, bhh, lstm_in, pre);
    lstm_kernel <<<1, 64, 0, stream>>>(pre, Whh, hs);
    final_kernel<<<32, 256, 0, stream>>>(lstm_in, hs, Wt, bt, Wa, ba, out);
}

// Round 3
// 4948.795 us; speedup vs baseline: 2.1483x; 2.1483x over previous
//
#include <hip/hip_runtime.h>
#include <hip/hip_bf16.h>
#include <math.h>

#define LAG   8192
#define NROW  32768        // LAG * 4 tweets
#define DIMD  1024

typedef __attribute__((ext_vector_type(8))) short  short8;   // 8 bf16 (4 VGPRs)
typedef __attribute__((ext_vector_type(4))) float  f32x4;    // mfma acc
typedef unsigned short ushort_t;

// fp32 -> (bf16 hi, bf16 lo) split, RNE both. f = hi + lo + O(2^-18 * f)
__device__ __forceinline__ void split2(float f, ushort_t& hi, ushort_t& lo) {
    unsigned u = __float_as_uint(f);
    unsigned r = u + 0x7FFFu + ((u >> 16) & 1u);
    ushort_t h = (ushort_t)(r >> 16);
    float hf = __uint_as_float((unsigned)h << 16);
    float lf = f - hf;
    unsigned u2 = __float_as_uint(lf);
    unsigned r2 = u2 + 0x7FFFu + ((u2 >> 16) & 1u);
    hi = h;
    lo = (ushort_t)(r2 >> 16);
}

__device__ __forceinline__ float rdp(const ushort_t* __restrict__ h,
                                     const ushort_t* __restrict__ l, size_t i) {
    return __uint_as_float((unsigned)h[i] << 16) + __uint_as_float((unsigned)l[i] << 16);
}

// ============================================================================
// bf16x3 split MFMA GEMM: C[M,1024] = act(A @ B + bias)
// block 128x128, BK=32, 4 waves (2x2), wave 64x64 = 4x4 mfma_f32_16x16x32_bf16,
// 3 mfma per tile (hi*hi + hi*lo + lo*hi)  ->  ~fp32 accuracy.
// AMODE 0: A = bf16 hi/lo planes (Ap, Ap2). AMODE 1: A = fp32 Ap + Ap2 (text+pos).
// B: fp32 [1024][1024] row-major, split in staging (k-strided coalesced loads).
// CMODE 0: fp32 out (Cf). CMODE 1: bf16 hi/lo plane out (Ch, Cl).
// ============================================================================
template<int AMODE, int CMODE, bool BIAS, bool RELU>
__global__ __launch_bounds__(256) void mgemm(
    const void* __restrict__ Ap, const void* __restrict__ Ap2,
    const float* __restrict__ Bf, const float* __restrict__ bias,
    float* __restrict__ Cf, ushort_t* __restrict__ Ch, ushort_t* __restrict__ Cl)
{
    // row stride 40 ushorts = 80 B: 16B-aligned b128 reads, worst 2-way bank alias (free)
    __shared__ ushort_t As_h[128*40], As_l[128*40], Bs_h[128*40], Bs_l[128*40];
    const int tid  = threadIdx.x;
    const int lane = tid & 63;
    const int wave = tid >> 6;
    const int wm   = (wave & 1) * 64;
    const int wn   = (wave >> 1) * 64;
    const int ln15 = lane & 15;
    const int q8   = (lane >> 4) * 8;
    const int row0 = blockIdx.y * 128;
    const int col0 = blockIdx.x * 128;

    const int ar  = tid >> 1;          // A stage: row 0..127
    const int ako = (tid & 1) << 4;    //          k offset 0/16
    const int bn  = tid & 127;         // B stage: col 0..127
    const int bk  = (tid >> 7) << 4;   //          k offset 0/16

    f32x4 acc[4][4] = {};

    for (int k0 = 0; k0 < DIMD; k0 += 32) {
        short8 a0, a1, c0, c1;
        if constexpr (AMODE == 0) {
            const ushort_t* Ah = (const ushort_t*)Ap  + (size_t)(row0+ar)*DIMD + k0 + ako;
            const ushort_t* Al = (const ushort_t*)Ap2 + (size_t)(row0+ar)*DIMD + k0 + ako;
            a0 = *(const short8*)Ah;  a1 = *(const short8*)(Ah + 8);
            c0 = *(const short8*)Al;  c1 = *(const short8*)(Al + 8);
        } else {
            const float* Af = (const float*)Ap  + (size_t)(row0+ar)*DIMD + k0 + ako;
            const float* A2 = (const float*)Ap2 + (size_t)(row0+ar)*DIMD + k0 + ako;
            ushort_t th[16], tl[16];
            #pragma unroll
            for (int i = 0; i < 16; i += 4) {
                float4 v = *(const float4*)(Af + i);
                float4 p = *(const float4*)(A2 + i);
                split2(v.x + p.x, th[i+0], tl[i+0]);
                split2(v.y + p.y, th[i+1], tl[i+1]);
                split2(v.z + p.z, th[i+2], tl[i+2]);
                split2(v.w + p.w, th[i+3], tl[i+3]);
            }
            a0 = *(short8*)&th[0]; a1 = *(short8*)&th[8];
            c0 = *(short8*)&tl[0]; c1 = *(short8*)&tl[8];
        }
        ushort_t bhv[16], blv[16];
        {
            const float* Bp = Bf + (size_t)(k0 + bk)*DIMD + col0 + bn;
            #pragma unroll
            for (int i = 0; i < 16; ++i)
                split2(Bp[(size_t)i*DIMD], bhv[i], blv[i]);
        }
        __syncthreads();
        *(short8*)&As_h[ar*40 + ako]     = a0;
        *(short8*)&As_h[ar*40 + ako + 8] = a1;
        *(short8*)&As_l[ar*40 + ako]     = c0;
        *(short8*)&As_l[ar*40 + ako + 8] = c1;
        *(short8*)&Bs_h[bn*40 + bk]      = *(short8*)&bhv[0];
        *(short8*)&Bs_h[bn*40 + bk + 8]  = *(short8*)&bhv[8];
        *(short8*)&Bs_l[bn*40 + bk]      = *(short8*)&blv[0];
        *(short8*)&Bs_l[bn*40 + bk + 8]  = *(short8*)&blv[8];
        __syncthreads();

        short8 fah[4], fal[4];
        #pragma unroll
        for (int i = 0; i < 4; ++i) {
            fah[i] = *(const short8*)&As_h[(wm + 16*i + ln15)*40 + q8];
            fal[i] = *(const short8*)&As_l[(wm + 16*i + ln15)*40 + q8];
        }
        #pragma unroll
        for (int j = 0; j < 4; ++j) {
            short8 fbh = *(const short8*)&Bs_h[(wn + 16*j + ln15)*40 + q8];
            short8 fbl = *(const short8*)&Bs_l[(wn + 16*j + ln15)*40 + q8];
            #pragma unroll
            for (int i = 0; i < 4; ++i) {
                acc[i][j] = __builtin_amdgcn_mfma_f32_16x16x32_bf16(fal[i], fbh, acc[i][j], 0, 0, 0);
                acc[i][j] = __builtin_amdgcn_mfma_f32_16x16x32_bf16(fah[i], fbl, acc[i][j], 0, 0, 0);
                acc[i][j] = __builtin_amdgcn_mfma_f32_16x16x32_bf16(fah[i], fbh, acc[i][j], 0, 0, 0);
            }
        }
    }

    // epilogue: C/D layout col=lane&15, row=(lane>>4)*4+reg  [m89-verified]
    #pragma unroll
    for (int j = 0; j < 4; ++j) {
        const int col = col0 + wn + 16*j + ln15;
        float bv = 0.f;
        if constexpr (BIAS) bv = bias[col];
        #pragma unroll
        for (int i = 0; i < 4; ++i) {
            #pragma unroll
            for (int r = 0; r < 4; ++r) {
                const int row = row0 + wm + 16*i + (lane >> 4)*4 + r;
                float v = acc[i][j][r] + bv;
                if constexpr (RELU) v = fmaxf(v, 0.f);
                if constexpr (CMODE == 0) {
                    Cf[(size_t)row*DIMD + col] = v;
                } else {
                    ushort_t hh, ll;
                    split2(v, hh, ll);
                    Ch[(size_t)row*DIMD + col] = hh;
                    Cl[(size_t)row*DIMD + col] = ll;
                }
            }
        }
    }
}

// ============================================================================
// fp32 tiled GEMM (kept for the two tiny 1024^3 precomputes Wqk, Wvo)
// ============================================================================
template<bool TRANS_B>
__global__ __launch_bounds__(256) void gemm_f32(
    const float* __restrict__ A, const float* __restrict__ B, float* __restrict__ C)
{
    __shared__ float As[16][132];
    __shared__ float Bs[16][132];
    const int tid  = threadIdx.x;
    const int tx   = tid & 15;
    const int ty   = tid >> 4;
    const int row0 = blockIdx.y * 128;
    const int col0 = blockIdx.x * 128;

    float acc[8][8];
    #pragma unroll
    for (int i = 0; i < 8; ++i)
        #pragma unroll
        for (int j = 0; j < 8; ++j) acc[i][j] = 0.f;

    for (int k0 = 0; k0 < DIMD; k0 += 16) {
        #pragma unroll
        for (int t = 0; t < 2; ++t) {
            int i  = tid + t * 256;
            int arr = i >> 2, ak = (i & 3) << 2;
            float4 av = *(const float4*)(A + (size_t)(row0 + arr) * DIMD + k0 + ak);
            As[ak + 0][arr] = av.x; As[ak + 1][arr] = av.y;
            As[ak + 2][arr] = av.z; As[ak + 3][arr] = av.w;
            if constexpr (TRANS_B) {
                float4 bv4 = *(const float4*)(B + (size_t)(col0 + arr) * DIMD + k0 + ak);
                Bs[ak + 0][arr] = bv4.x; Bs[ak + 1][arr] = bv4.y;
                Bs[ak + 2][arr] = bv4.z; Bs[ak + 3][arr] = bv4.w;
            } else {
                int br = i >> 5, bc = (i & 31) << 2;
                *(float4*)&Bs[br][bc] =
                    *(const float4*)(B + (size_t)(k0 + br) * DIMD + col0 + bc);
            }
        }
        __syncthreads();
        #pragma unroll
        for (int kk = 0; kk < 16; ++kk) {
            float a[8], b[8];
            *(float4*)&a[0] = *(const float4*)&As[kk][ty * 8];
            *(float4*)&a[4] = *(const float4*)&As[kk][ty * 8 + 4];
            *(float4*)&b[0] = *(const float4*)&Bs[kk][tx * 4];
            *(float4*)&b[4] = *(const float4*)&Bs[kk][64 + tx * 4];
            #pragma unroll
            for (int i = 0; i < 8; ++i)
                #pragma unroll
                for (int j = 0; j < 8; ++j)
                    acc[i][j] = fmaf(a[i], b[j], acc[i][j]);
        }
        __syncthreads();
    }
    #pragma unroll
    for (int i = 0; i < 8; ++i) {
        size_t rr = (size_t)(row0 + ty * 8 + i) * DIMD;
        *(float4*)(C + rr + col0 + tx * 4)      = *(float4*)&acc[i][0];
        *(float4*)(C + rr + col0 + 64 + tx * 4) = *(float4*)&acc[i][4];
    }
}

// ============================================================================
// Multi-head (16) attention over k=4, planes in, planes out IN-PLACE over q.
// ============================================================================
__global__ __launch_bounds__(256) void attn1_kernel(
    ushort_t* qh, ushort_t* ql,
    const ushort_t* __restrict__ kh, const ushort_t* __restrict__ kl,
    const ushort_t* __restrict__ vh, const ushort_t* __restrict__ vl)
{
    const int l    = blockIdx.x;
    const int qi   = threadIdx.x >> 6;
    const int lane = threadIdx.x & 63;
    const size_t base = (size_t)l * 4 * DIMD;
    const float scale = 0.125f;     // 1/sqrt(64)

    #pragma unroll 1
    for (int h = 0; h < 16; ++h) {
        int off = h * 64 + lane;
        float qv = rdp(qh, ql, base + qi * DIMD + off);
        float s0 = qv * rdp(kh, kl, base + 0 * DIMD + off);
        float s1 = qv * rdp(kh, kl, base + 1 * DIMD + off);
        float s2 = qv * rdp(kh, kl, base + 2 * DIMD + off);
        float s3 = qv * rdp(kh, kl, base + 3 * DIMD + off);
        #pragma unroll
        for (int d = 1; d < 64; d <<= 1) {
            s0 += __shfl_xor(s0, d);
            s1 += __shfl_xor(s1, d);
            s2 += __shfl_xor(s2, d);
            s3 += __shfl_xor(s3, d);
        }
        s0 *= scale; s1 *= scale; s2 *= scale; s3 *= scale;
        float mx = fmaxf(fmaxf(s0, s1), fmaxf(s2, s3));
        float e0 = expf(s0 - mx), e1 = expf(s1 - mx);
        float e2 = expf(s2 - mx), e3 = expf(s3 - mx);
        float inv = 1.f / (e0 + e1 + e2 + e3);
        e0 *= inv; e1 *= inv; e2 *= inv; e3 *= inv;
        float r = e0 * rdp(vh, vl, base + 0 * DIMD + off)
                + e1 * rdp(vh, vl, base + 1 * DIMD + off)
                + e2 * rdp(vh, vl, base + 2 * DIMD + off)
                + e3 * rdp(vh, vl, base + 3 * DIMD + off);
        split2(r, qh[base + qi * DIMD + off], ql[base + qi * DIMD + off]);
    }
}

// ============================================================================
// Single-head attention, algebraically fused (t = x@Wqk, vo = x@Wvo):
// m written IN-PLACE over t (fp32).  x comes in as bf16 planes.
// ============================================================================
__global__ __launch_bounds__(256) void attn2_kernel(
    const ushort_t* __restrict__ xh, const ushort_t* __restrict__ xl,
    const float* __restrict__ vo, float* t)
{
    const int l    = blockIdx.x;
    const int qi   = threadIdx.x >> 6;
    const int lane = threadIdx.x & 63;
    const size_t base = (size_t)l * 4 * DIMD;

    float s0 = 0.f, s1 = 0.f, s2 = 0.f, s3 = 0.f;
    #pragma unroll
    for (int c = 0; c < 16; ++c) {
        int off = c * 64 + lane;
        float tv = t[base + qi * DIMD + off];
        s0 = fmaf(tv, rdp(xh, xl, base + 0 * DIMD + off), s0);
        s1 = fmaf(tv, rdp(xh, xl, base + 1 * DIMD + off), s1);
        s2 = fmaf(tv, rdp(xh, xl, base + 2 * DIMD + off), s2);
        s3 = fmaf(tv, rdp(xh, xl, base + 3 * DIMD + off), s3);
    }
    #pragma unroll
    for (int d = 1; d < 64; d <<= 1) {
        s0 += __shfl_xor(s0, d);
        s1 += __shfl_xor(s1, d);
        s2 += __shfl_xor(s2, d);
        s3 += __shfl_xor(s3, d);
    }
    const float scale = 0.03125f;   // 1/sqrt(1024)
    s0 *= scale; s1 *= scale; s2 *= scale; s3 *= scale;
    float mx = fmaxf(fmaxf(s0, s1), fmaxf(s2, s3));
    float e0 = expf(s0 - mx), e1 = expf(s1 - mx);
    float e2 = expf(s2 - mx), e3 = expf(s3 - mx);
    float inv = 1.f / (e0 + e1 + e2 + e3);
    e0 *= inv; e1 *= inv; e2 *= inv; e3 *= inv;
    #pragma unroll
    for (int c = 0; c < 16; ++c) {
        int off = c * 64 + lane;
        float r = e0 * vo[base + 0 * DIMD + off] + e1 * vo[base + 1 * DIMD + off]
                + e2 * vo[base + 2 * DIMD + off] + e3 * vo[base + 3 * DIMD + off];
        t[base + qi * DIMD + off] = r;
    }
}

// ============================================================================
// y = LayerNorm(inter + text + pos) * g + b  -> bf16 hi/lo planes
// ============================================================================
__global__ __launch_bounds__(256) void ln_kernel(
    const float* __restrict__ inter, const float* __restrict__ text,
    const float* __restrict__ pos, const float* __restrict__ g,
    const float* __restrict__ b, ushort_t* __restrict__ yh, ushort_t* __restrict__ yl)
{
    const int row  = blockIdx.x * 4 + (threadIdx.x >> 6);
    const int lane = threadIdx.x & 63;
    const size_t base = (size_t)row * DIMD;
    float v[16];
    float s = 0.f;
    #pragma unroll
    for (int c = 0; c < 16; ++c) {
        int off = c * 64 + lane;
        v[c] = inter[base + off] + text[base + off] + pos[base + off];
        s += v[c];
    }
    #pragma unroll
    for (int d = 1; d < 64; d <<= 1) s += __shfl_xor(s, d);
    float mu = s * (1.f / 1024.f);
    float vs = 0.f;
    #pragma unroll
    for (int c = 0; c < 16; ++c) { float t = v[c] - mu; vs += t * t; }
    #pragma unroll
    for (int d = 1; d < 64; d <<= 1) vs += __shfl_xor(vs, d);
    float rs = rsqrtf(vs * (1.f / 1024.f) + 1e-5f);
    #pragma unroll
    for (int c = 0; c < 16; ++c) {
        int off = c * 64 + lane;
        float y = (v[c] - mu) * rs * g[off] + b[off];
        split2(y, yh[base + off], yl[base + off]);
    }
}

// ============================================================================
// att = softmax(w_u^T @ tanh(w_m)) -- one block, 1024 threads.
// ============================================================================
__global__ __launch_bounds__(1024) void att_kernel(
    const float* __restrict__ w_u, const float* __restrict__ w_m,
    float* __restrict__ att)
{
    __shared__ float tj[1024];
    __shared__ float red[16];
    const int tid = threadIdx.x;
    tj[tid] = tanhf(w_m[tid]);
    __syncthreads();
    float a = 0.f;
    #pragma unroll 8
    for (int j = 0; j < 1024; ++j)
        a = fmaf(w_u[(size_t)j * 1024 + tid], tj[j], a);
    float m = a;
    #pragma unroll
    for (int d = 1; d < 64; d <<= 1) m = fmaxf(m, __shfl_xor(m, d));
    if ((tid & 63) == 0) red[tid >> 6] = m;
    __syncthreads();
    if (tid < 16) {
        float x = red[tid];
        #pragma unroll
        for (int d = 1; d < 16; d <<= 1) x = fmaxf(x, __shfl_xor(x, d));
        red[tid] = x;
    }
    __syncthreads();
    float mx = red[0];
    float e = expf(a - mx);
    float s = e;
    #pragma unroll
    for (int d = 1; d < 64; d <<= 1) s += __shfl_xor(s, d);
    __syncthreads();
    if ((tid & 63) == 0) red[tid >> 6] = s;
    __syncthreads();
    if (tid < 16) {
        float x = red[tid];
        #pragma unroll
        for (int d = 1; d < 16; d <<= 1) x += __shfl_xor(x, d);
        red[tid] = x;
    }
    __syncthreads();
    att[tid] = e / red[0];
}

// ============================================================================
// out_k[l,k] = m[l,k,:]·att ; lstm_in ; pre = lstm_in@Wih^T + biases (grouped)
// ============================================================================
__global__ __launch_bounds__(256) void outk_kernel(
    const float* __restrict__ m, const float* __restrict__ prices,
    const float* __restrict__ att, const float* __restrict__ Wih,
    const float* __restrict__ bih, const float* __restrict__ bhh,
    float* __restrict__ lstm_in, float* __restrict__ pre)
{
    const int l    = blockIdx.x;
    const int w    = threadIdx.x >> 6;
    const int lane = threadIdx.x & 63;
    __shared__ float li[9];
    float acc = 0.f;
    const size_t base = ((size_t)l * 4 + w) * DIMD;
    #pragma unroll
    for (int c = 0; c < 16; ++c) {
        int off = c * 64 + lane;
        acc = fmaf(m[base + off], att[off], acc);
    }
    #pragma unroll
    for (int d = 1; d < 64; d <<= 1) acc += __shfl_xor(acc, d);
    if (lane == 0) li[w] = acc;
    if (threadIdx.x >= 64 && threadIdx.x < 69)
        li[4 + threadIdx.x - 64] = prices[(size_t)l * 5 + threadIdx.x - 64];
    __syncthreads();
    if (threadIdx.x < 9) lstm_in[(size_t)l * 9 + threadIdx.x] = li[threadIdx.x];
    if (threadIdx.x < 20) {
        int g = threadIdx.x;
        float p = bih[g] + bhh[g];
        #pragma unroll
        for (int j = 0; j < 9; ++j) p = fmaf(li[j], Wih[g * 9 + j], p);
        pre[(size_t)l * 20 + (g % 5) * 4 + (g / 5)] = p;
    }
}

// ============================================================================
// Sequential LSTM, single wave, FAST transcendentals (v_exp_f32 + v_rcp_f32).
// ============================================================================
__device__ __forceinline__ float bcast(float x, int srclane) {
    return __uint_as_float(__builtin_amdgcn_readlane(__float_as_uint(x), srclane));
}
__device__ __forceinline__ float fsig(float x) {
    return __builtin_amdgcn_rcpf(1.f + __expf(-x));
}
__device__ __forceinline__ float ftanh(float x) {
    float e = __expf(-2.f * x);     // finite for |x| < 44; gates stay << that
    return (1.f - e) * __builtin_amdgcn_rcpf(1.f + e);
}

__global__ __launch_bounds__(64) void lstm_kernel(
    const float* __restrict__ pre, const float* __restrict__ Whh,
    float* __restrict__ hs)
{
    const int lane = threadIdx.x;
    const int m    = (lane < 5) ? lane : 0;
    float wi[5], wf[5], wg[5], wo[5];
    #pragma unroll
    for (int j = 0; j < 5; ++j) {
        wi[j] = Whh[( 0 + m) * 5 + j];
        wf[j] = Whh[( 5 + m) * 5 + j];
        wg[j] = Whh[(10 + m) * 5 + j];
        wo[j] = Whh[(15 + m) * 5 + j];
    }
    float cm = 0.f, hm = 0.f;
    float sh0 = 0.f, sh1 = 0.f, sh2 = 0.f, sh3 = 0.f, sh4 = 0.f;

    float4 buf[8];
    #pragma unroll
    for (int j = 0; j < 8; ++j)
        buf[j] = *(const float4*)(pre + (size_t)j * 20 + m * 4);

    for (int l0 = 0; l0 < LAG; l0 += 8) {
        #pragma unroll
        for (int j = 0; j < 8; ++j) {
            float4 p = buf[j];
            buf[j] = *(const float4*)(pre + (size_t)(l0 + 8 + j) * 20 + m * 4);
            float gi = p.x, gf = p.y, gg = p.z, go = p.w;
            gi = fmaf(sh0, wi[0], gi); gf = fmaf(sh0, wf[0], gf);
            gg = fmaf(sh0, wg[0], gg); go = fmaf(sh0, wo[0], go);
            gi = fmaf(sh1, wi[1], gi); gf = fmaf(sh1, wf[1], gf);
            gg = fmaf(sh1, wg[1], gg); go = fmaf(sh1, wo[1], go);
            gi = fmaf(sh2, wi[2], gi); gf = fmaf(sh2, wf[2], gf);
            gg = fmaf(sh2, wg[2], gg); go = fmaf(sh2, wo[2], go);
            gi = fmaf(sh3, wi[3], gi); gf = fmaf(sh3, wf[3], gf);
            gg = fmaf(sh3, wg[3], gg); go = fmaf(sh3, wo[3], go);
            gi = fmaf(sh4, wi[4], gi); gf = fmaf(sh4, wf[4], gf);
            gg = fmaf(sh4, wg[4], gg); go = fmaf(sh4, wo[4], go);
            float si = fsig(gi);
            float sf = fsig(gf);
            float tg = ftanh(gg);
            float so = fsig(go);
            cm = fmaf(sf, cm, si * tg);
            hm = so * ftanh(cm);
            if (lane < 5) hs[(size_t)(l0 + j) * 5 + m] = hm;
            sh0 = bcast(hm, 0); sh1 = bcast(hm, 1); sh2 = bcast(hm, 2);
            sh3 = bcast(hm, 3); sh4 = bcast(hm, 4);
        }
    }
}

// ============================================================================
// final / auxiliary heads
// ============================================================================
__global__ __launch_bounds__(256) void final_kernel(
    const float* __restrict__ lstm_in, const float* __restrict__ hs,
    const float* __restrict__ Wt, const float* __restrict__ bt,
    const float* __restrict__ Wa, const float* __restrict__ ba,
    float* __restrict__ out)
{
    const int l = blockIdx.x * 256 + threadIdx.x;   // 0..8191
    float f[14];
    #pragma unroll
    for (int j = 0; j < 9; ++j) f[j] = lstm_in[(size_t)l * 9 + j];
    #pragma unroll
    for (int j = 0; j < 5; ++j) f[9 + j] = hs[(size_t)l * 5 + j];
    #pragma unroll
    for (int c = 0; c < 2; ++c) {
        float a = bt[c], b = ba[c];
        #pragma unroll
        for (int j = 0; j < 14; ++j) {
            a = fmaf(f[j], Wt[j * 2 + c], a);
            b = fmaf(f[j], Wa[j * 2 + c], b);
        }
        out[(size_t)l * 2 + c]         = a;
        out[16384 + (size_t)l * 2 + c] = b;
    }
}

// ============================================================================
extern "C" void kernel_launch(void* const* d_in, const int* in_sizes, int n_in,
                              void* d_out, int out_size, void* d_ws, size_t ws_size,
                              hipStream_t stream)
{
    const float* text   = (const float*)d_in[0];
    const float* prices = (const float*)d_in[1];
    const float* pos    = (const float*)d_in[2];
    const float* Wq1    = (const float*)d_in[3];
    const float* Wk1    = (const float*)d_in[4];
    const float* Wv1    = (const float*)d_in[5];
    const float* Wo1    = (const float*)d_in[6];
    const float* ln_g   = (const float*)d_in[7];
    const float* ln_b   = (const float*)d_in[8];
    const float* W1     = (const float*)d_in[9];
    const float* b1     = (const float*)d_in[10];
    const float* W2     = (const float*)d_in[11];
    const float* b2     = (const float*)d_in[12];
    const float* Wq2    = (const float*)d_in[13];
    const float* Wk2    = (const float*)d_in[14];
    const float* Wv2    = (const float*)d_in[15];
    const float* Wo2    = (const float*)d_in[16];
    const float* w_u    = (const float*)d_in[17];
    const float* w_m    = (const float*)d_in[18];
    const float* Wih    = (const float*)d_in[19];
    const float* Whh    = (const float*)d_in[20];
    const float* bih    = (const float*)d_in[21];
    const float* bhh    = (const float*)d_in[22];
    const float* Wt     = (const float*)d_in[23];
    const float* bt     = (const float*)d_in[24];
    const float* Wa     = (const float*)d_in[25];
    const float* ba     = (const float*)d_in[26];

    float* ws = (float*)d_ws;
    const size_t BUF = (size_t)NROW * DIMD;         // 33,554,432 floats = 128 MB
    const size_t PL  = (size_t)NROW * DIMD;         // plane elems (ushort)
    float* A  = ws;
    float* B  = ws + BUF;
    float* C  = ws + 2 * BUF;
    float* Wqk_f   = ws + 3 * BUF;                  // [1024,1024] fp32
    float* Wvo_f   = Wqk_f + (size_t)DIMD * DIMD;
    float* att     = Wvo_f + (size_t)DIMD * DIMD;
    float* lstm_in = att + 1024;
    float* pre     = lstm_in + (size_t)LAG * 9;
    float* hs      = pre + ((size_t)LAG * 20 + 320);
    float* out     = (float*)d_out;
    // total ws: 3*BUF + ~2.38M floats  = 412.16 MB (== round-2-validated size)

    // plane views of the big buffers (hi plane, then lo plane)
    ushort_t* Ahp = (ushort_t*)A;  ushort_t* Alp = Ahp + PL;
    ushort_t* Bhp = (ushort_t*)B;  ushort_t* Blp = Bhp + PL;
    ushort_t* Chp = (ushort_t*)C;  ushort_t* Clp = Chp + PL;

    dim3 ggrid(8, 256), gblk(256);                  // M=32768 mgemms
    dim3 sgrid(8, 8);                               // 1024^3 fp32 gemms

    // precomputes (independent of big pipeline)
    att_kernel<<<1, 1024, 0, stream>>>(w_u, w_m, att);
    gemm_f32<true ><<<sgrid, gblk, 0, stream>>>(Wq2, Wk2, Wqk_f);   // Wq2 @ Wk2^T
    gemm_f32<false><<<sgrid, gblk, 0, stream>>>(Wv2, Wo2, Wvo_f);   // Wv2 @ Wo2

    // transformer encoder (all big GEMMs = bf16x3 MFMA)
    mgemm<1,1,false,false><<<ggrid, gblk, 0, stream>>>(text, pos, Wq1, nullptr, nullptr, Ahp, Alp);
    mgemm<1,1,false,false><<<ggrid, gblk, 0, stream>>>(text, pos, Wk1, nullptr, nullptr, Bhp, Blp);
    mgemm<1,1,false,false><<<ggrid, gblk, 0, stream>>>(text, pos, Wv1, nullptr, nullptr, Chp, Clp);
    attn1_kernel<<<LAG, 256, 0, stream>>>(Ahp, Alp, Bhp, Blp, Chp, Clp);        // -> A planes
    mgemm<0,0,false,false><<<ggrid, gblk, 0, stream>>>(Ahp, Alp, Wo1, nullptr, B, nullptr, nullptr); // inter fp32
    ln_kernel<<<LAG, 256, 0, stream>>>(B, text, pos, ln_g, ln_b, Chp, Clp);     // y planes
    mgemm<0,1,true ,true ><<<ggrid, gblk, 0, stream>>>(Chp, Clp, W1, b1, nullptr, Ahp, Alp);  // relu planes
    mgemm<0,1,true ,false><<<ggrid, gblk, 0, stream>>>(Ahp, Alp, W2, b2, nullptr, Bhp, Blp);  // ffn planes
    mgemm<0,0,false,false><<<ggrid, gblk, 0, stream>>>(Bhp, Blp, Wqk_f, nullptr, C, nullptr, nullptr); // t fp32
    mgemm<0,0,false,false><<<ggrid, gblk, 0, stream>>>(Bhp, Blp, Wvo_f, nullptr, A, nullptr, nullptr); // vo fp32
    attn2_kernel<<<LAG, 256, 0, stream>>>(Bhp, Blp, A, C);                      // m -> C (in-place over t)

    // temporal head
    outk_kernel <<<LAG, 256, 0, stream>>>(C, prices, att, Wih, bih, bhh, lstm_in, pre);
    lstm_kernel <<<1, 64, 0, stream>>>(pre, Whh, hs);
    final_kernel<<<32, 256, 0, stream>>>(lstm_in, hs, Wt, bt, Wa, ba, out);
}

// Round 4
// 3996.970 us; speedup vs baseline: 2.6599x; 1.2381x over previous
//
#include <hip/hip_runtime.h>
#include <hip/hip_bf16.h>
#include <math.h>

#define LAG   8192
#define NROW  32768        // LAG * 4 tweets
#define DIMD  1024

typedef __attribute__((ext_vector_type(8))) short  short8;   // 8 bf16 (4 VGPRs)
typedef __attribute__((ext_vector_type(4))) float  f32x4;    // mfma acc
typedef __attribute__((ext_vector_type(2))) float  f32x2;
typedef unsigned short ushort_t;
typedef unsigned int   uint_t;

// fp32 -> packed (bf16 hi | bf16 lo << 16), RNE both. f ~= hi + lo (err ~2^-18*f)
__device__ __forceinline__ uint_t split2_pack(float f) {
    unsigned u = __float_as_uint(f);
    unsigned r = u + 0x7FFFu + ((u >> 16) & 1u);
    unsigned h = r >> 16;
    float hf = __uint_as_float(h << 16);
    float lf = f - hf;
    unsigned u2 = __float_as_uint(lf);
    unsigned r2 = u2 + 0x7FFFu + ((u2 >> 16) & 1u);
    return h | (r2 & 0xFFFF0000u);
}
// packed -> fp32 value
__device__ __forceinline__ float updp(uint_t p) {
    return __uint_as_float(p << 16) + __uint_as_float(p & 0xFFFF0000u);
}

// unpack 16 packed uints -> hi-plane 16B x2 and lo-plane 16B x2 (v_perm pairs)
__device__ __forceinline__ void unpack16(const uint_t* r, uint4& h0, uint4& h1,
                                         uint4& l0, uint4& l1) {
    h0.x = __builtin_amdgcn_perm(r[1],  r[0],  0x05040100u);
    h0.y = __builtin_amdgcn_perm(r[3],  r[2],  0x05040100u);
    h0.z = __builtin_amdgcn_perm(r[5],  r[4],  0x05040100u);
    h0.w = __builtin_amdgcn_perm(r[7],  r[6],  0x05040100u);
    h1.x = __builtin_amdgcn_perm(r[9],  r[8],  0x05040100u);
    h1.y = __builtin_amdgcn_perm(r[11], r[10], 0x05040100u);
    h1.z = __builtin_amdgcn_perm(r[13], r[12], 0x05040100u);
    h1.w = __builtin_amdgcn_perm(r[15], r[14], 0x05040100u);
    l0.x = __builtin_amdgcn_perm(r[1],  r[0],  0x07060302u);
    l0.y = __builtin_amdgcn_perm(r[3],  r[2],  0x07060302u);
    l0.z = __builtin_amdgcn_perm(r[5],  r[4],  0x07060302u);
    l0.w = __builtin_amdgcn_perm(r[7],  r[6],  0x07060302u);
    l1.x = __builtin_amdgcn_perm(r[9],  r[8],  0x07060302u);
    l1.y = __builtin_amdgcn_perm(r[11], r[10], 0x07060302u);
    l1.z = __builtin_amdgcn_perm(r[13], r[12], 0x07060302u);
    l1.w = __builtin_amdgcn_perm(r[15], r[14], 0x07060302u);
}

// ============================================================================
// bf16x3 split MFMA GEMM: C[M,1024] = act(A @ B + bias)
// block 128x128, BK=32, 4 waves (2x2), wave 64x64 = 4x4 mfma_f32_16x16x32_bf16,
// 3 mfma per tile (hh + hl + lh) -> ~fp32 accuracy.
// A: always packed planes. BM 1: B packed planes.  BM 0: B fp32 (split here).
// CM 0: fp32 out.  CM 1: packed plane out.
// k-loop software-pipelined: next tile's global loads issued under MFMA.
// ============================================================================
template<int BM, int CM, bool BIAS, bool RELU>
__global__ __launch_bounds__(256) void mgemm(
    const uint_t* __restrict__ Apk, const void* __restrict__ Bsrc,
    const float* __restrict__ bias,
    float* __restrict__ Cf, uint_t* __restrict__ Cp)
{
    // row stride 40 ushorts = 80 B: 16B-aligned b128, worst 2-way bank alias (free)
    __shared__ ushort_t As_h[128*40], As_l[128*40], Bs_h[128*40], Bs_l[128*40];
    const int tid  = threadIdx.x;
    const int lane = tid & 63;
    const int wave = tid >> 6;
    const int wm   = (wave & 1) * 64;
    const int wn   = (wave >> 1) * 64;
    const int ln15 = lane & 15;
    const int q8   = (lane >> 4) * 8;
    const int row0 = blockIdx.y * 128;
    const int col0 = blockIdx.x * 128;

    const int ar  = tid >> 1;          // A stage: row 0..127
    const int ako = (tid & 1) << 4;    //          k offset 0/16
    const int bn  = tid & 127;         // B stage: col 0..127
    const int bk  = (tid >> 7) << 4;   //          k offset 0/16

    f32x4 acc[4][4] = {};

    uint_t a_r[16] __attribute__((aligned(16)));
    uint_t b_r[16] __attribute__((aligned(16)));

    // preload k0 = 0
    {
        const uint_t* Apt = Apk + (size_t)(row0 + ar) * DIMD + ako;
        *(uint4*)&a_r[0]  = *(const uint4*)(Apt + 0);
        *(uint4*)&a_r[4]  = *(const uint4*)(Apt + 4);
        *(uint4*)&a_r[8]  = *(const uint4*)(Apt + 8);
        *(uint4*)&a_r[12] = *(const uint4*)(Apt + 12);
        if constexpr (BM == 1) {
            const uint_t* Bpt = (const uint_t*)Bsrc + (size_t)bk * DIMD + col0 + bn;
            #pragma unroll
            for (int i = 0; i < 16; ++i) b_r[i] = Bpt[(size_t)i * DIMD];
        } else {
            const float* Bpt = (const float*)Bsrc + (size_t)bk * DIMD + col0 + bn;
            #pragma unroll
            for (int i = 0; i < 16; ++i) b_r[i] = split2_pack(Bpt[(size_t)i * DIMD]);
        }
    }

    for (int k0 = 0; k0 < DIMD; k0 += 32) {
        __syncthreads();   // previous iteration's fragment reads complete
        {
            uint4 h0, h1, l0, l1;
            unpack16(a_r, h0, h1, l0, l1);
            *(uint4*)&As_h[ar*40 + ako]     = h0;
            *(uint4*)&As_h[ar*40 + ako + 8] = h1;
            *(uint4*)&As_l[ar*40 + ako]     = l0;
            *(uint4*)&As_l[ar*40 + ako + 8] = l1;
            unpack16(b_r, h0, h1, l0, l1);
            *(uint4*)&Bs_h[bn*40 + bk]      = h0;
            *(uint4*)&Bs_h[bn*40 + bk + 8]  = h1;
            *(uint4*)&Bs_l[bn*40 + bk]      = l0;
            *(uint4*)&Bs_l[bn*40 + bk + 8]  = l1;
        }
        __syncthreads();

        if (k0 + 32 < DIMD) {   // issue next tile's loads; they drain under MFMA
            const int kn = k0 + 32;
            const uint_t* Apt = Apk + (size_t)(row0 + ar) * DIMD + kn + ako;
            *(uint4*)&a_r[0]  = *(const uint4*)(Apt + 0);
            *(uint4*)&a_r[4]  = *(const uint4*)(Apt + 4);
            *(uint4*)&a_r[8]  = *(const uint4*)(Apt + 8);
            *(uint4*)&a_r[12] = *(const uint4*)(Apt + 12);
            if constexpr (BM == 1) {
                const uint_t* Bpt = (const uint_t*)Bsrc + (size_t)(kn + bk) * DIMD + col0 + bn;
                #pragma unroll
                for (int i = 0; i < 16; ++i) b_r[i] = Bpt[(size_t)i * DIMD];
            } else {
                const float* Bpt = (const float*)Bsrc + (size_t)(kn + bk) * DIMD + col0 + bn;
                #pragma unroll
                for (int i = 0; i < 16; ++i) b_r[i] = split2_pack(Bpt[(size_t)i * DIMD]);
            }
        }

        short8 fah[4], fal[4];
        #pragma unroll
        for (int i = 0; i < 4; ++i) {
            fah[i] = *(const short8*)&As_h[(wm + 16*i + ln15)*40 + q8];
            fal[i] = *(const short8*)&As_l[(wm + 16*i + ln15)*40 + q8];
        }
        #pragma unroll
        for (int j = 0; j < 4; ++j) {
            short8 fbh = *(const short8*)&Bs_h[(wn + 16*j + ln15)*40 + q8];
            short8 fbl = *(const short8*)&Bs_l[(wn + 16*j + ln15)*40 + q8];
            #pragma unroll
            for (int i = 0; i < 4; ++i) {
                acc[i][j] = __builtin_amdgcn_mfma_f32_16x16x32_bf16(fal[i], fbh, acc[i][j], 0, 0, 0);
                acc[i][j] = __builtin_amdgcn_mfma_f32_16x16x32_bf16(fah[i], fbl, acc[i][j], 0, 0, 0);
                acc[i][j] = __builtin_amdgcn_mfma_f32_16x16x32_bf16(fah[i], fbh, acc[i][j], 0, 0, 0);
            }
        }
    }

    // epilogue: C/D layout col=lane&15, row=(lane>>4)*4+reg  [m89-verified]
    #pragma unroll
    for (int j = 0; j < 4; ++j) {
        const int col = col0 + wn + 16*j + ln15;
        float bv = 0.f;
        if constexpr (BIAS) bv = bias[col];
        #pragma unroll
        for (int i = 0; i < 4; ++i) {
            #pragma unroll
            for (int r = 0; r < 4; ++r) {
                const int row = row0 + wm + 16*i + (lane >> 4)*4 + r;
                float v = acc[i][j][r] + bv;
                if constexpr (RELU) v = fmaxf(v, 0.f);
                if constexpr (CM == 0) Cf[(size_t)row*DIMD + col] = v;
                else                   Cp[(size_t)row*DIMD + col] = split2_pack(v);
            }
        }
    }
}

// ============================================================================
// fp32 tiled GEMM (two tiny 1024^3 precomputes Wqk, Wvo)
// ============================================================================
template<bool TRANS_B>
__global__ __launch_bounds__(256) void gemm_f32(
    const float* __restrict__ A, const float* __restrict__ B, float* __restrict__ C)
{
    __shared__ float As[16][132];
    __shared__ float Bs[16][132];
    const int tid  = threadIdx.x;
    const int tx   = tid & 15;
    const int ty   = tid >> 4;
    const int row0 = blockIdx.y * 128;
    const int col0 = blockIdx.x * 128;

    float acc[8][8];
    #pragma unroll
    for (int i = 0; i < 8; ++i)
        #pragma unroll
        for (int j = 0; j < 8; ++j) acc[i][j] = 0.f;

    for (int k0 = 0; k0 < DIMD; k0 += 16) {
        #pragma unroll
        for (int t = 0; t < 2; ++t) {
            int i  = tid + t * 256;
            int arr = i >> 2, ak = (i & 3) << 2;
            float4 av = *(const float4*)(A + (size_t)(row0 + arr) * DIMD + k0 + ak);
            As[ak + 0][arr] = av.x; As[ak + 1][arr] = av.y;
            As[ak + 2][arr] = av.z; As[ak + 3][arr] = av.w;
            if constexpr (TRANS_B) {
                float4 bv4 = *(const float4*)(B + (size_t)(col0 + arr) * DIMD + k0 + ak);
                Bs[ak + 0][arr] = bv4.x; Bs[ak + 1][arr] = bv4.y;
                Bs[ak + 2][arr] = bv4.z; Bs[ak + 3][arr] = bv4.w;
            } else {
                int br = i >> 5, bc = (i & 31) << 2;
                *(float4*)&Bs[br][bc] =
                    *(const float4*)(B + (size_t)(k0 + br) * DIMD + col0 + bc);
            }
        }
        __syncthreads();
        #pragma unroll
        for (int kk = 0; kk < 16; ++kk) {
            float a[8], b[8];
            *(float4*)&a[0] = *(const float4*)&As[kk][ty * 8];
            *(float4*)&a[4] = *(const float4*)&As[kk][ty * 8 + 4];
            *(float4*)&b[0] = *(const float4*)&Bs[kk][tx * 4];
            *(float4*)&b[4] = *(const float4*)&Bs[kk][64 + tx * 4];
            #pragma unroll
            for (int i = 0; i < 8; ++i)
                #pragma unroll
                for (int j = 0; j < 8; ++j)
                    acc[i][j] = fmaf(a[i], b[j], acc[i][j]);
        }
        __syncthreads();
    }
    #pragma unroll
    for (int i = 0; i < 8; ++i) {
        size_t rr = (size_t)(row0 + ty * 8 + i) * DIMD;
        *(float4*)(C + rr + col0 + tx * 4)      = *(float4*)&acc[i][0];
        *(float4*)(C + rr + col0 + 64 + tx * 4) = *(float4*)&acc[i][4];
    }
}

// ============================================================================
// pack a fp32 matrix (n elems, mult of 1024) into packed hi/lo planes
// ============================================================================
__global__ __launch_bounds__(256) void splitw_kernel(
    const float* __restrict__ in, uint_t* __restrict__ out)
{
    const size_t i = ((size_t)blockIdx.x * 256 + threadIdx.x) * 4;
    float4 v = *(const float4*)(in + i);
    uint4 o;
    o.x = split2_pack(v.x); o.y = split2_pack(v.y);
    o.z = split2_pack(v.z); o.w = split2_pack(v.w);
    *(uint4*)(out + i) = o;
}

// x = text + pos -> packed planes
__global__ __launch_bounds__(256) void splitx_kernel(
    const float* __restrict__ text, const float* __restrict__ pos,
    uint_t* __restrict__ out)
{
    const size_t i = ((size_t)blockIdx.x * 256 + threadIdx.x) * 4;
    float4 a = *(const float4*)(text + i);
    float4 b = *(const float4*)(pos + i);
    uint4 o;
    o.x = split2_pack(a.x + b.x); o.y = split2_pack(a.y + b.y);
    o.z = split2_pack(a.z + b.z); o.w = split2_pack(a.w + b.w);
    *(uint4*)(out + i) = o;
}

// ============================================================================
// attn1 phase 1: 16-head scores + softmax -> prob[l][qi][h][kk]
// ============================================================================
__global__ __launch_bounds__(256) void score_kernel(
    const uint_t* __restrict__ q, const uint_t* __restrict__ k,
    float* __restrict__ prob)
{
    const int l    = blockIdx.x;
    const int qi   = threadIdx.x >> 6;
    const int lane = threadIdx.x & 63;
    const size_t base = (size_t)l * 4 * DIMD;
    const float scale = 0.125f;     // 1/sqrt(64)

    #pragma unroll 1
    for (int h = 0; h < 16; ++h) {
        int off = h * 64 + lane;
        float qv = updp(q[base + qi * DIMD + off]);
        float s0 = qv * updp(k[base + 0 * DIMD + off]);
        float s1 = qv * updp(k[base + 1 * DIMD + off]);
        float s2 = qv * updp(k[base + 2 * DIMD + off]);
        float s3 = qv * updp(k[base + 3 * DIMD + off]);
        #pragma unroll
        for (int d = 1; d < 64; d <<= 1) {
            s0 += __shfl_xor(s0, d);
            s1 += __shfl_xor(s1, d);
            s2 += __shfl_xor(s2, d);
            s3 += __shfl_xor(s3, d);
        }
        s0 *= scale; s1 *= scale; s2 *= scale; s3 *= scale;
        float mx = fmaxf(fmaxf(s0, s1), fmaxf(s2, s3));
        float e0 = expf(s0 - mx), e1 = expf(s1 - mx);
        float e2 = expf(s2 - mx), e3 = expf(s3 - mx);
        float inv = 1.f / (e0 + e1 + e2 + e3);
        if (lane == 0) {
            float4 p = { e0 * inv, e1 * inv, e2 * inv, e3 * inv };
            *(float4*)&prob[(((size_t)l * 4 + qi) * 16 + h) * 4] = p;
        }
    }
}

// attn1 phase 2: o[qi] = sum_kk p * v[kk]  (chunk c == head h)
__global__ __launch_bounds__(256) void mix_kernel(
    const uint_t* __restrict__ v, const float* __restrict__ prob,
    uint_t* __restrict__ o)
{
    const int l    = blockIdx.x;
    const int qi   = threadIdx.x >> 6;
    const int lane = threadIdx.x & 63;
    const size_t base = (size_t)l * 4 * DIMD;
    #pragma unroll
    for (int c = 0; c < 16; ++c) {
        int off = c * 64 + lane;
        float4 p = *(const float4*)&prob[(((size_t)l * 4 + qi) * 16 + c) * 4];
        float r = p.x * updp(v[base + 0 * DIMD + off])
                + p.y * updp(v[base + 1 * DIMD + off])
                + p.z * updp(v[base + 2 * DIMD + off])
                + p.w * updp(v[base + 3 * DIMD + off]);
        o[base + qi * DIMD + off] = split2_pack(r);
    }
}

// ============================================================================
// Single-head attention, algebraically fused (t = x@Wqk, vo = x@Wvo):
// m written IN-PLACE over t (fp32). x = packed planes.
// ============================================================================
__global__ __launch_bounds__(256) void attn2_kernel(
    const uint_t* __restrict__ xp, const float* __restrict__ vo, float* t)
{
    const int l    = blockIdx.x;
    const int qi   = threadIdx.x >> 6;
    const int lane = threadIdx.x & 63;
    const size_t base = (size_t)l * 4 * DIMD;

    float s0 = 0.f, s1 = 0.f, s2 = 0.f, s3 = 0.f;
    #pragma unroll
    for (int c = 0; c < 16; ++c) {
        int off = c * 64 + lane;
        float tv = t[base + qi * DIMD + off];
        s0 = fmaf(tv, updp(xp[base + 0 * DIMD + off]), s0);
        s1 = fmaf(tv, updp(xp[base + 1 * DIMD + off]), s1);
        s2 = fmaf(tv, updp(xp[base + 2 * DIMD + off]), s2);
        s3 = fmaf(tv, updp(xp[base + 3 * DIMD + off]), s3);
    }
    #pragma unroll
    for (int d = 1; d < 64; d <<= 1) {
        s0 += __shfl_xor(s0, d);
        s1 += __shfl_xor(s1, d);
        s2 += __shfl_xor(s2, d);
        s3 += __shfl_xor(s3, d);
    }
    const float scale = 0.03125f;   // 1/sqrt(1024)
    s0 *= scale; s1 *= scale; s2 *= scale; s3 *= scale;
    float mx = fmaxf(fmaxf(s0, s1), fmaxf(s2, s3));
    float e0 = expf(s0 - mx), e1 = expf(s1 - mx);
    float e2 = expf(s2 - mx), e3 = expf(s3 - mx);
    float inv = 1.f / (e0 + e1 + e2 + e3);
    e0 *= inv; e1 *= inv; e2 *= inv; e3 *= inv;
    #pragma unroll
    for (int c = 0; c < 16; ++c) {
        int off = c * 64 + lane;
        float r = e0 * vo[base + 0 * DIMD + off] + e1 * vo[base + 1 * DIMD + off]
                + e2 * vo[base + 2 * DIMD + off] + e3 * vo[base + 3 * DIMD + off];
        t[base + qi * DIMD + off] = r;
    }
}

// ============================================================================
// y = LayerNorm(inter + text + pos) * g + b  -> packed planes
// ============================================================================
__global__ __launch_bounds__(256) void ln_kernel(
    const float* __restrict__ inter, const float* __restrict__ text,
    const float* __restrict__ pos, const float* __restrict__ g,
    const float* __restrict__ b, uint_t* __restrict__ yp)
{
    const int row  = blockIdx.x * 4 + (threadIdx.x >> 6);
    const int lane = threadIdx.x & 63;
    const size_t base = (size_t)row * DIMD;
    float v[16];
    float s = 0.f;
    #pragma unroll
    for (int c = 0; c < 16; ++c) {
        int off = c * 64 + lane;
        v[c] = inter[base + off] + text[base + off] + pos[base + off];
        s += v[c];
    }
    #pragma unroll
    for (int d = 1; d < 64; d <<= 1) s += __shfl_xor(s, d);
    float mu = s * (1.f / 1024.f);
    float vs = 0.f;
    #pragma unroll
    for (int c = 0; c < 16; ++c) { float t = v[c] - mu; vs += t * t; }
    #pragma unroll
    for (int d = 1; d < 64; d <<= 1) vs += __shfl_xor(vs, d);
    float rs = rsqrtf(vs * (1.f / 1024.f) + 1e-5f);
    #pragma unroll
    for (int c = 0; c < 16; ++c) {
        int off = c * 64 + lane;
        float y = (v[c] - mu) * rs * g[off] + b[off];
        yp[base + off] = split2_pack(y);
    }
}

// ============================================================================
// att = softmax(w_u^T @ tanh(w_m)) -- one block, 1024 threads.
// ============================================================================
__global__ __launch_bounds__(1024) void att_kernel(
    const float* __restrict__ w_u, const float* __restrict__ w_m,
    float* __restrict__ att)
{
    __shared__ float tj[1024];
    __shared__ float red[16];
    const int tid = threadIdx.x;
    tj[tid] = tanhf(w_m[tid]);
    __syncthreads();
    float a = 0.f;
    #pragma unroll 8
    for (int j = 0; j < 1024; ++j)
        a = fmaf(w_u[(size_t)j * 1024 + tid], tj[j], a);
    float m = a;
    #pragma unroll
    for (int d = 1; d < 64; d <<= 1) m = fmaxf(m, __shfl_xor(m, d));
    if ((tid & 63) == 0) red[tid >> 6] = m;
    __syncthreads();
    if (tid < 16) {
        float x = red[tid];
        #pragma unroll
        for (int d = 1; d < 16; d <<= 1) x = fmaxf(x, __shfl_xor(x, d));
        red[tid] = x;
    }
    __syncthreads();
    float mx = red[0];
    float e = expf(a - mx);
    float s = e;
    #pragma unroll
    for (int d = 1; d < 64; d <<= 1) s += __shfl_xor(s, d);
    __syncthreads();
    if ((tid & 63) == 0) red[tid >> 6] = s;
    __syncthreads();
    if (tid < 16) {
        float x = red[tid];
        #pragma unroll
        for (int d = 1; d < 16; d <<= 1) x += __shfl_xor(x, d);
        red[tid] = x;
    }
    __syncthreads();
    att[tid] = e / red[0];
}

// ============================================================================
// out_k[l,k] = m[l,k,:]·att ; lstm_in ; pre = lstm_in@Wih^T + biases (grouped)
// ============================================================================
__global__ __launch_bounds__(256) void outk_kernel(
    const float* __restrict__ m, const float* __restrict__ prices,
    const float* __restrict__ att, const float* __restrict__ Wih,
    const float* __restrict__ bih, const float* __restrict__ bhh,
    float* __restrict__ lstm_in, float* __restrict__ pre)
{
    const int l    = blockIdx.x;
    const int w    = threadIdx.x >> 6;
    const int lane = threadIdx.x & 63;
    __shared__ float li[9];
    float acc = 0.f;
    const size_t base = ((size_t)l * 4 + w) * DIMD;
    #pragma unroll
    for (int c = 0; c < 16; ++c) {
        int off = c * 64 + lane;
        acc = fmaf(m[base + off], att[off], acc);
    }
    #pragma unroll
    for (int d = 1; d < 64; d <<= 1) acc += __shfl_xor(acc, d);
    if (lane == 0) li[w] = acc;
    if (threadIdx.x >= 64 && threadIdx.x < 69)
        li[4 + threadIdx.x - 64] = prices[(size_t)l * 5 + threadIdx.x - 64];
    __syncthreads();
    if (threadIdx.x < 9) lstm_in[(size_t)l * 9 + threadIdx.x] = li[threadIdx.x];
    if (threadIdx.x < 20) {
        int g = threadIdx.x;
        float p = bih[g] + bhh[g];
        #pragma unroll
        for (int j = 0; j < 9; ++j) p = fmaf(li[j], Wih[g * 9 + j], p);
        pre[(size_t)l * 20 + (g % 5) * 4 + (g / 5)] = p;
    }
}

// ============================================================================
// Sequential LSTM, single wave. Packed float2 gate math, tree dots,
// exec-mask-free store (lanes>=5 duplicate unit 0's value), 16-deep prefetch.
// ============================================================================
__device__ __forceinline__ float bcast(float x, int srclane) {
    return __uint_as_float(__builtin_amdgcn_readlane(__float_as_uint(x), srclane));
}
__device__ __forceinline__ float fsig(float x) {
    return __builtin_amdgcn_rcpf(1.f + __expf(-x));
}
__device__ __forceinline__ float ftanh(float x) {
    float e = __expf(-2.f * x);
    return (1.f - e) * __builtin_amdgcn_rcpf(1.f + e);
}

__global__ __launch_bounds__(64) void lstm_kernel(
    const float* __restrict__ pre, const float* __restrict__ Whh,
    float* __restrict__ hs)
{
    const int lane = threadIdx.x;
    const int m    = (lane < 5) ? lane : 0;
    f32x2 wif[5], wgo[5];
    #pragma unroll
    for (int j = 0; j < 5; ++j) {
        wif[j] = (f32x2){ Whh[( 0 + m) * 5 + j], Whh[( 5 + m) * 5 + j] };
        wgo[j] = (f32x2){ Whh[(10 + m) * 5 + j], Whh[(15 + m) * 5 + j] };
    }
    float cm = 0.f, hm = 0.f;
    float s0 = 0.f, s1 = 0.f, s2 = 0.f, s3 = 0.f, s4 = 0.f;

    float4 buf[16];
    #pragma unroll
    for (int j = 0; j < 16; ++j)
        buf[j] = *(const float4*)(pre + (size_t)j * 20 + m * 4);

    for (int l0 = 0; l0 < LAG; l0 += 16) {
        #pragma unroll
        for (int j = 0; j < 16; ++j) {
            float4 p = buf[j];
            buf[j] = *(const float4*)(pre + (size_t)(l0 + 16 + j) * 20 + m * 4);
            f32x2 S0 = { s0, s0 }, S1 = { s1, s1 }, S2 = { s2, s2 };
            f32x2 S3 = { s3, s3 }, S4 = { s4, s4 };
            f32x2 gif = { p.x, p.y };
            f32x2 ggo = { p.z, p.w };
            // tree: depth 3 instead of 5
            f32x2 t1 = S0 * wif[0] + gif;
            f32x2 t2 = S1 * wif[1] + S2 * wif[2];
            f32x2 t3 = S3 * wif[3] + S4 * wif[4];
            gif = t1 + t2 + t3;
            f32x2 u1 = S0 * wgo[0] + ggo;
            f32x2 u2 = S1 * wgo[1] + S2 * wgo[2];
            f32x2 u3 = S3 * wgo[3] + S4 * wgo[4];
            ggo = u1 + u2 + u3;
            float si = fsig(gif.x);
            float sf = fsig(gif.y);
            float tg = ftanh(ggo.x);
            float so = fsig(ggo.y);
            cm = fmaf(sf, cm, si * tg);
            hm = so * ftanh(cm);
            hs[(size_t)(l0 + j) * 5 + m] = hm;    // lanes>=5 dup lane0's value
            s0 = bcast(hm, 0); s1 = bcast(hm, 1); s2 = bcast(hm, 2);
            s3 = bcast(hm, 3); s4 = bcast(hm, 4);
        }
    }
}

// ============================================================================
// final / auxiliary heads
// ============================================================================
__global__ __launch_bounds__(256) void final_kernel(
    const float* __restrict__ lstm_in, const float* __restrict__ hs,
    const float* __restrict__ Wt, const float* __restrict__ bt,
    const float* __restrict__ Wa, const float* __restrict__ ba,
    float* __restrict__ out)
{
    const int l = blockIdx.x * 256 + threadIdx.x;   // 0..8191
    float f[14];
    #pragma unroll
    for (int j = 0; j < 9; ++j) f[j] = lstm_in[(size_t)l * 9 + j];
    #pragma unroll
    for (int j = 0; j < 5; ++j) f[9 + j] = hs[(size_t)l * 5 + j];
    #pragma unroll
    for (int c = 0; c < 2; ++c) {
        float a = bt[c], b = ba[c];
        #pragma unroll
        for (int j = 0; j < 14; ++j) {
            a = fmaf(f[j], Wt[j * 2 + c], a);
            b = fmaf(f[j], Wa[j * 2 + c], b);
        }
        out[(size_t)l * 2 + c]         = a;
        out[16384 + (size_t)l * 2 + c] = b;
    }
}

// ============================================================================
extern "C" void kernel_launch(void* const* d_in, const int* in_sizes, int n_in,
                              void* d_out, int out_size, void* d_ws, size_t ws_size,
                              hipStream_t stream)
{
    const float* text   = (const float*)d_in[0];
    const float* prices = (const float*)d_in[1];
    const float* pos    = (const float*)d_in[2];
    const float* Wq1    = (const float*)d_in[3];
    const float* Wk1    = (const float*)d_in[4];
    const float* Wv1    = (const float*)d_in[5];
    const float* Wo1    = (const float*)d_in[6];
    const float* ln_g   = (const float*)d_in[7];
    const float* ln_b   = (const float*)d_in[8];
    const float* W1     = (const float*)d_in[9];
    const float* b1     = (const float*)d_in[10];
    const float* W2     = (const float*)d_in[11];
    const float* b2     = (const float*)d_in[12];
    const float* Wq2    = (const float*)d_in[13];
    const float* Wk2    = (const float*)d_in[14];
    const float* Wv2    = (const float*)d_in[15];
    const float* Wo2    = (const float*)d_in[16];
    const float* w_u    = (const float*)d_in[17];
    const float* w_m    = (const float*)d_in[18];
    const float* Wih    = (const float*)d_in[19];
    const float* Whh    = (const float*)d_in[20];
    const float* bih    = (const float*)d_in[21];
    const float* bhh    = (const float*)d_in[22];
    const float* Wt     = (const float*)d_in[23];
    const float* bt     = (const float*)d_in[24];
    const float* Wa     = (const float*)d_in[25];
    const float* ba     = (const float*)d_in[26];

    float* ws = (float*)d_ws;
    const size_t BUF = (size_t)NROW * DIMD;         // 33,554,432 elems / buffer
    const size_t MW  = (size_t)DIMD * DIMD;         // 1,048,576
    float* A = ws;                                  // packed or fp32 views
    float* B = ws + BUF;
    float* C = ws + 2 * BUF;
    float* WqkF = ws + 3 * BUF;
    float* WvoF = WqkF + MW;
    float* att  = WvoF + MW;                        // 1024
    float* U    = att + 1024;                       // union: prob | lstm area
    float* prob    = U;                             // LAG*4*16*4 = 2,097,152
    float* lstm_in = U;                             // (after prob is dead)
    float* pre     = lstm_in + (size_t)LAG * 9;     // LAG*20 + 400 pad
    float* hs      = pre + ((size_t)LAG * 20 + 400);
    uint_t* Wpk    = (uint_t*)(U + 2097152);        // 8 x MW packed weights
    float* out     = (float*)d_out;

    const size_t need_base = ((size_t)(3 * BUF) + 2 * MW + 1024 + 2097152) * 4;
    const size_t need_full = need_base + 8 * MW * 4;
    const bool full = ws_size >= need_full;

    uint_t* Ap = (uint_t*)A;
    uint_t* Bp = (uint_t*)B;
    uint_t* Cp = (uint_t*)C;

    dim3 ggrid(8, 256), gblk(256);                  // M=32768 mgemms
    dim3 sgrid(8, 8);                               // 1024^3 fp32 gemms

    // precomputes (independent of big pipeline)
    att_kernel<<<1, 1024, 0, stream>>>(w_u, w_m, att);
    gemm_f32<true ><<<sgrid, gblk, 0, stream>>>(Wq2, Wk2, WqkF);   // Wq2 @ Wk2^T
    gemm_f32<false><<<sgrid, gblk, 0, stream>>>(Wv2, Wo2, WvoF);   // Wv2 @ Wo2

    splitx_kernel<<<32768, 256, 0, stream>>>(text, pos, Ap);       // x planes -> A

    if (full) {
        splitw_kernel<<<1024, 256, 0, stream>>>(Wq1,  Wpk + 0 * MW);
        splitw_kernel<<<1024, 256, 0, stream>>>(Wk1,  Wpk + 1 * MW);
        splitw_kernel<<<1024, 256, 0, stream>>>(Wv1,  Wpk + 2 * MW);
        splitw_kernel<<<1024, 256, 0, stream>>>(Wo1,  Wpk + 3 * MW);
        splitw_kernel<<<1024, 256, 0, stream>>>(W1,   Wpk + 4 * MW);
        splitw_kernel<<<1024, 256, 0, stream>>>(W2,   Wpk + 5 * MW);
        splitw_kernel<<<1024, 256, 0, stream>>>(WqkF, Wpk + 6 * MW);
        splitw_kernel<<<1024, 256, 0, stream>>>(WvoF, Wpk + 7 * MW);

        mgemm<1,1,false,false><<<ggrid, gblk, 0, stream>>>(Ap, Wpk + 0*MW, nullptr, nullptr, Bp); // q
        mgemm<1,1,false,false><<<ggrid, gblk, 0, stream>>>(Ap, Wpk + 1*MW, nullptr, nullptr, Cp); // k
        score_kernel<<<LAG, 256, 0, stream>>>(Bp, Cp, prob);
        mgemm<1,1,false,false><<<ggrid, gblk, 0, stream>>>(Ap, Wpk + 2*MW, nullptr, nullptr, Bp); // v (q dead)
        mix_kernel<<<LAG, 256, 0, stream>>>(Bp, prob, Cp);                                        // o (k dead)
        mgemm<1,0,false,false><<<ggrid, gblk, 0, stream>>>(Cp, Wpk + 3*MW, nullptr, A, nullptr);  // inter (x dead)
        ln_kernel<<<LAG, 256, 0, stream>>>(A, text, pos, ln_g, ln_b, Bp);                         // y (v dead)
        mgemm<1,1,true ,true ><<<ggrid, gblk, 0, stream>>>(Bp, Wpk + 4*MW, b1, nullptr, Cp);      // relu (o dead)
        mgemm<1,1,true ,false><<<ggrid, gblk, 0, stream>>>(Cp, Wpk + 5*MW, b2, nullptr, Ap);      // ffn (inter dead)
        mgemm<1,0,false,false><<<ggrid, gblk, 0, stream>>>(Ap, Wpk + 6*MW, nullptr, B, nullptr);  // t (y dead)
        mgemm<1,0,false,false><<<ggrid, gblk, 0, stream>>>(Ap, Wpk + 7*MW, nullptr, C, nullptr);  // vo (relu dead)
    } else {
        mgemm<0,1,false,false><<<ggrid, gblk, 0, stream>>>(Ap, Wq1,  nullptr, nullptr, Bp);
        mgemm<0,1,false,false><<<ggrid, gblk, 0, stream>>>(Ap, Wk1,  nullptr, nullptr, Cp);
        score_kernel<<<LAG, 256, 0, stream>>>(Bp, Cp, prob);
        mgemm<0,1,false,false><<<ggrid, gblk, 0, stream>>>(Ap, Wv1,  nullptr, nullptr, Bp);
        mix_kernel<<<LAG, 256, 0, stream>>>(Bp, prob, Cp);
        mgemm<0,0,false,false><<<ggrid, gblk, 0, stream>>>(Cp, Wo1,  nullptr, A, nullptr);
        ln_kernel<<<LAG, 256, 0, stream>>>(A, text, pos, ln_g, ln_b, Bp);
        mgemm<0,1,true ,true ><<<ggrid, gblk, 0, stream>>>(Bp, W1,   b1, nullptr, Cp);
        mgemm<0,1,true ,false><<<ggrid, gblk, 0, stream>>>(Cp, W2,   b2, nullptr, Ap);
        mgemm<0,0,false,false><<<ggrid, gblk, 0, stream>>>(Ap, WqkF, nullptr, B, nullptr);
        mgemm<0,0,false,false><<<ggrid, gblk, 0, stream>>>(Ap, WvoF, nullptr, C, nullptr);
    }
    attn2_kernel<<<LAG, 256, 0, stream>>>(Ap, C, B);                // m -> B (in-place over t)

    // temporal head
    outk_kernel <<<LAG, 256, 0, stream>>>(B, prices, att, Wih, bih, bhh, lstm_in, pre);
    lstm_kernel <<<1, 64, 0, stream>>>(pre, Whh, hs);
    final_kernel<<<32, 256, 0, stream>>>(lstm_in, hs, Wt, bt, Wa, ba, out);
}